// Round 1
// baseline (5038.480 us; speedup 1.0000x reference)
//
#include <hip/hip_runtime.h>
#include <hip/hip_bf16.h>

#define EPSV 1e-5f

// workspace float offsets
#define WS_SUM0   0
#define WS_SSQ0   64
#define WS_SUM1   128
#define WS_SSQ1   192
#define WS_SUM2   256
#define WS_SSQ2   320
#define WS_AL0    384
#define WS_BE0    448
#define WS_ZBG    512
#define WS_T1BG   576      // 64*32
#define WS_AL1    2624
#define WS_BE1    2688
#define WS_T2BG   2752     // 64*16
#define WS_AL2    3776
#define WS_BE2    3840
#define WS_A2BG   3904     // 64*16
#define WS_OC     4928     // 9 used

// ---------------------------------------------------------------------------
// Kernel 1: BN0 statistics over the active 16 conv positions (y<4, x<4).
// thread: tid -> mg = tid&3 (4 m per block-iter), k = tid>>2
__global__ __launch_bounds__(256) void k_stats0(
    const int* __restrict__ x, const float* __restrict__ conv_w,
    const float* __restrict__ conv_b, float* __restrict__ ws, int M) {
  __shared__ float sW[8000];
  for (int i = threadIdx.x; i < 8000; i += 256) sW[i] = conv_w[i];
  __syncthreads();
  const int tid = threadIdx.x;
  const int mg = tid & 3;
  const int k  = tid >> 2;
  const float cb = conv_b[k];
  const float* Wk = &sW[k * 125];
  float s = 0.f, ss = 0.f;
  for (int m = blockIdx.x * 4 + mg; m < M; m += gridDim.x * 4) {
    int r[5], c[5];
#pragma unroll
    for (int cc = 0; cc < 5; ++cc) {
      r[cc] = x[m * 10 + cc * 2];
      c[cc] = x[m * 10 + cc * 2 + 1];
    }
#pragma unroll
    for (int y = 0; y < 4; ++y) {
#pragma unroll
      for (int xx = 0; xx < 4; ++xx) {
        float v = cb;
#pragma unroll
        for (int cc = 0; cc < 5; ++cc) {
          int di = r[cc] - y, dj = c[cc] - xx;
          if (di >= 0 && di < 5 && dj >= 0 && dj < 5) v += Wk[cc * 25 + di * 5 + dj];
        }
        s += v;
        ss += v * v;
      }
    }
  }
  s  += __shfl_xor(s, 1);  s  += __shfl_xor(s, 2);
  ss += __shfl_xor(ss, 1); ss += __shfl_xor(ss, 2);
  if (mg == 0) {
    atomicAdd(&ws[WS_SUM0 + k], s);
    atomicAdd(&ws[WS_SSQ0 + k], ss);
  }
}

// ---------------------------------------------------------------------------
// Kernel 2: finalize BN0; compute background chain r1_bg -> t1_bg; seed BN1
// stats with the background contribution.
__global__ __launch_bounds__(64) void k_fin0(
    const float* __restrict__ conv_b, const float* __restrict__ g0,
    const float* __restrict__ b0, const float* __restrict__ w_rank,
    const float* __restrict__ b_rank, const float* __restrict__ w_h1,
    const float* __restrict__ b_h1, float* __restrict__ ws, int M) {
  __shared__ float sS[32];
  const int t = threadIdx.x;
  if (t < 32) {
    float su = 0.f;
    for (int s2 = 0; s2 < 10; ++s2) su += w_rank[t * 10 + s2];
    sS[t] = su;
  }
  __syncthreads();
  const int k = t;
  const float n0 = 110.f * (float)M;
  const float cb = conv_b[k];
  const float S  = ws[WS_SUM0 + k] + 94.f * (float)M * cb;
  const float SS = ws[WS_SSQ0 + k] + 94.f * (float)M * cb * cb;
  const float mu = S / n0;
  const float var = SS / n0 - mu * mu;
  const float rstd = rsqrtf(var + EPSV);
  const float al = rstd * g0[k];
  const float be = b0[k] - mu * al;
  ws[WS_AL0 + k] = al;
  ws[WS_BE0 + k] = be;
  const float zbg = fmaxf(cb * al + be, 0.f);
  ws[WS_ZBG + k] = zbg;
  float r1bg[32];
#pragma unroll
  for (int o = 0; o < 32; ++o) r1bg[o] = fmaxf(zbg * sS[o] + b_rank[o], 0.f);
  float sb = 0.f, ssb = 0.f;
  for (int o = 0; o < 32; ++o) {
    float acc = b_h1[o];
#pragma unroll
    for (int i = 0; i < 32; ++i) acc += r1bg[i] * w_h1[o * 32 + i];
    ws[WS_T1BG + k * 32 + o] = acc;
    sb += acc;
    ssb += acc * acc;
  }
  ws[WS_SUM1 + k] = 7.f * (float)M * sb;   // overwrite (stats1 atomics add later)
  ws[WS_SSQ1 + k] = 7.f * (float)M * ssb;
}

// ---------------------------------------------------------------------------
// Kernel 3: BN1 statistics: recompute v -> a0 -> r1 -> t1 over active rows.
// thread: y = tid&3 (active row), k = tid>>2. One m per block-iteration.
__global__ __launch_bounds__(256) void k_stats1(
    const int* __restrict__ x, const float* __restrict__ conv_w,
    const float* __restrict__ conv_b, const float* __restrict__ w_rank,
    const float* __restrict__ b_rank, const float* __restrict__ w_h1,
    const float* __restrict__ b_h1, float* __restrict__ ws, int M) {
  __shared__ float sW[8000];
  __shared__ float sWr[320], sBr[32], sCr[32];
  __shared__ float sW1[1024], sB1[32];
  __shared__ float sAl[64], sBe[64], sZ[64];
  for (int i = threadIdx.x; i < 8000; i += 256) sW[i] = conv_w[i];
  for (int i = threadIdx.x; i < 320; i += 256) sWr[i] = w_rank[i];
  for (int i = threadIdx.x; i < 1024; i += 256) sW1[i] = w_h1[i];
  if (threadIdx.x < 32) {
    sBr[threadIdx.x] = b_rank[threadIdx.x];
    sB1[threadIdx.x] = b_h1[threadIdx.x];
    float cu = 0.f;
    for (int s2 = 4; s2 < 10; ++s2) cu += w_rank[threadIdx.x * 10 + s2];
    sCr[threadIdx.x] = cu;
  }
  if (threadIdx.x < 64) {
    sAl[threadIdx.x] = ws[WS_AL0 + threadIdx.x];
    sBe[threadIdx.x] = ws[WS_BE0 + threadIdx.x];
    sZ[threadIdx.x]  = ws[WS_ZBG + threadIdx.x];
  }
  __syncthreads();
  const int tid = threadIdx.x;
  const int y = tid & 3, k = tid >> 2;
  const float cb = conv_b[k];
  const float al = sAl[k], be = sBe[k], zbg = sZ[k];
  const float* Wk = &sW[k * 125];
  float s1 = 0.f, ss1 = 0.f;
  for (int m = blockIdx.x; m < M; m += gridDim.x) {
    int r[5], c[5];
#pragma unroll
    for (int cc = 0; cc < 5; ++cc) {
      r[cc] = x[m * 10 + cc * 2];
      c[cc] = x[m * 10 + cc * 2 + 1];
    }
    float a0[4];
#pragma unroll
    for (int xx = 0; xx < 4; ++xx) {
      float v = cb;
#pragma unroll
      for (int cc = 0; cc < 5; ++cc) {
        int di = r[cc] - y, dj = c[cc] - xx;
        if (di >= 0 && di < 5 && dj >= 0 && dj < 5) v += Wk[cc * 25 + di * 5 + dj];
      }
      a0[xx] = fmaxf(al * v + be, 0.f);
    }
    float r1[32];
#pragma unroll
    for (int o = 0; o < 32; ++o) {
      float acc = sBr[o] + zbg * sCr[o];
#pragma unroll
      for (int xx = 0; xx < 4; ++xx) acc += a0[xx] * sWr[o * 10 + xx];
      r1[o] = fmaxf(acc, 0.f);
    }
#pragma unroll
    for (int o = 0; o < 32; ++o) {
      float acc = sB1[o];
#pragma unroll
      for (int i = 0; i < 32; ++i) acc += r1[i] * sW1[o * 32 + i];
      s1 += acc;
      ss1 += acc * acc;
    }
  }
  s1  += __shfl_xor(s1, 1);  s1  += __shfl_xor(s1, 2);
  ss1 += __shfl_xor(ss1, 1); ss1 += __shfl_xor(ss1, 2);
  if (y == 0) {
    atomicAdd(&ws[WS_SUM1 + k], s1);
    atomicAdd(&ws[WS_SSQ1 + k], ss1);
  }
}

// ---------------------------------------------------------------------------
// Kernel 4: finalize BN1; background a1_bg -> t2_bg; seed BN2 stats.
__global__ __launch_bounds__(64) void k_fin1(
    const float* __restrict__ g1, const float* __restrict__ b1,
    const float* __restrict__ w_h2, const float* __restrict__ b_h2,
    float* __restrict__ ws, int M) {
  const int k = threadIdx.x;
  const float n1 = (float)M * 11.f * 32.f;
  const float S = ws[WS_SUM1 + k], SS = ws[WS_SSQ1 + k];
  const float mu = S / n1;
  const float var = SS / n1 - mu * mu;
  const float rstd = rsqrtf(var + EPSV);
  const float al = rstd * g1[k];
  const float be = b1[k] - mu * al;
  ws[WS_AL1 + k] = al;
  ws[WS_BE1 + k] = be;
  float a1bg[32];
#pragma unroll
  for (int o = 0; o < 32; ++o)
    a1bg[o] = fmaxf(al * ws[WS_T1BG + k * 32 + o] + be, 0.f);
  float sb = 0.f, ssb = 0.f;
  for (int p = 0; p < 16; ++p) {
    float acc = b_h2[p];
#pragma unroll
    for (int o = 0; o < 32; ++o) acc += a1bg[o] * w_h2[p * 32 + o];
    ws[WS_T2BG + k * 16 + p] = acc;
    sb += acc;
    ssb += acc * acc;
  }
  ws[WS_SUM2 + k] = 7.f * (float)M * sb;
  ws[WS_SSQ2 + k] = 7.f * (float)M * ssb;
}

// ---------------------------------------------------------------------------
// Kernel 5: BN2 statistics: recompute chain through t2 on active rows.
__global__ __launch_bounds__(256) void k_stats2(
    const int* __restrict__ x, const float* __restrict__ conv_w,
    const float* __restrict__ conv_b, const float* __restrict__ w_rank,
    const float* __restrict__ b_rank, const float* __restrict__ w_h1,
    const float* __restrict__ b_h1, const float* __restrict__ w_h2,
    const float* __restrict__ b_h2, float* __restrict__ ws, int M) {
  __shared__ float sW[8000];
  __shared__ float sWr[320], sBr[32], sCr[32];
  __shared__ float sW1[1024], sB1[32];
  __shared__ float sW2[512], sB2[16];
  __shared__ float sAl[64], sBe[64], sZ[64], sAl1[64], sBe1[64];
  for (int i = threadIdx.x; i < 8000; i += 256) sW[i] = conv_w[i];
  for (int i = threadIdx.x; i < 320; i += 256) sWr[i] = w_rank[i];
  for (int i = threadIdx.x; i < 1024; i += 256) sW1[i] = w_h1[i];
  for (int i = threadIdx.x; i < 512; i += 256) sW2[i] = w_h2[i];
  if (threadIdx.x < 32) {
    sBr[threadIdx.x] = b_rank[threadIdx.x];
    sB1[threadIdx.x] = b_h1[threadIdx.x];
    float cu = 0.f;
    for (int s2 = 4; s2 < 10; ++s2) cu += w_rank[threadIdx.x * 10 + s2];
    sCr[threadIdx.x] = cu;
  }
  if (threadIdx.x < 16) sB2[threadIdx.x] = b_h2[threadIdx.x];
  if (threadIdx.x < 64) {
    sAl[threadIdx.x]  = ws[WS_AL0 + threadIdx.x];
    sBe[threadIdx.x]  = ws[WS_BE0 + threadIdx.x];
    sZ[threadIdx.x]   = ws[WS_ZBG + threadIdx.x];
    sAl1[threadIdx.x] = ws[WS_AL1 + threadIdx.x];
    sBe1[threadIdx.x] = ws[WS_BE1 + threadIdx.x];
  }
  __syncthreads();
  const int tid = threadIdx.x;
  const int y = tid & 3, k = tid >> 2;
  const float cb = conv_b[k];
  const float al = sAl[k], be = sBe[k], zbg = sZ[k];
  const float al1 = sAl1[k], be1 = sBe1[k];
  const float* Wk = &sW[k * 125];
  float s2a = 0.f, ss2a = 0.f;
  for (int m = blockIdx.x; m < M; m += gridDim.x) {
    int r[5], c[5];
#pragma unroll
    for (int cc = 0; cc < 5; ++cc) {
      r[cc] = x[m * 10 + cc * 2];
      c[cc] = x[m * 10 + cc * 2 + 1];
    }
    float a0[4];
#pragma unroll
    for (int xx = 0; xx < 4; ++xx) {
      float v = cb;
#pragma unroll
      for (int cc = 0; cc < 5; ++cc) {
        int di = r[cc] - y, dj = c[cc] - xx;
        if (di >= 0 && di < 5 && dj >= 0 && dj < 5) v += Wk[cc * 25 + di * 5 + dj];
      }
      a0[xx] = fmaxf(al * v + be, 0.f);
    }
    float r1[32];
#pragma unroll
    for (int o = 0; o < 32; ++o) {
      float acc = sBr[o] + zbg * sCr[o];
#pragma unroll
      for (int xx = 0; xx < 4; ++xx) acc += a0[xx] * sWr[o * 10 + xx];
      r1[o] = fmaxf(acc, 0.f);
    }
    float a1[32];
#pragma unroll
    for (int o = 0; o < 32; ++o) {
      float acc = sB1[o];
#pragma unroll
      for (int i = 0; i < 32; ++i) acc += r1[i] * sW1[o * 32 + i];
      a1[o] = fmaxf(al1 * acc + be1, 0.f);
    }
#pragma unroll
    for (int p = 0; p < 16; ++p) {
      float acc = sB2[p];
#pragma unroll
      for (int o = 0; o < 32; ++o) acc += a1[o] * sW2[p * 32 + o];
      s2a += acc;
      ss2a += acc * acc;
    }
  }
  s2a  += __shfl_xor(s2a, 1);  s2a  += __shfl_xor(s2a, 2);
  ss2a += __shfl_xor(ss2a, 1); ss2a += __shfl_xor(ss2a, 2);
  if (y == 0) {
    atomicAdd(&ws[WS_SUM2 + k], s2a);
    atomicAdd(&ws[WS_SSQ2 + k], ss2a);
  }
}

// ---------------------------------------------------------------------------
// Kernel 6: finalize BN2; background a2_bg; background output constant.
__global__ __launch_bounds__(64) void k_fin2(
    const float* __restrict__ g2, const float* __restrict__ b2,
    const float* __restrict__ w_out, const float* __restrict__ b_out,
    float* __restrict__ ws, int M) {
  __shared__ float red[64 * 9];
  const int k = threadIdx.x;
  const float n2 = (float)M * 11.f * 16.f;
  const float S = ws[WS_SUM2 + k], SS = ws[WS_SSQ2 + k];
  const float mu = S / n2;
  const float var = SS / n2 - mu * mu;
  const float rstd = rsqrtf(var + EPSV);
  const float al = rstd * g2[k];
  const float be = b2[k] - mu * al;
  ws[WS_AL2 + k] = al;
  ws[WS_BE2 + k] = be;
  float a2bg[16];
#pragma unroll
  for (int p = 0; p < 16; ++p) {
    a2bg[p] = fmaxf(al * ws[WS_T2BG + k * 16 + p] + be, 0.f);
    ws[WS_A2BG + k * 16 + p] = a2bg[p];
  }
  for (int j = 0; j < 9; ++j) {
    float acc = 0.f;
#pragma unroll
    for (int p = 0; p < 16; ++p) {
      float wsum = 0.f;
#pragma unroll
      for (int yy = 4; yy < 11; ++yy)
        wsum += w_out[j * 11264 + k * 176 + yy * 16 + p];
      acc += a2bg[p] * wsum;
    }
    red[k * 9 + j] = acc;
  }
  __syncthreads();
  if (k < 9) {
    float acc = b_out[k];
    for (int t = 0; t < 64; ++t) acc += red[t * 9 + k];
    ws[WS_OC + k] = acc;
  }
}

// ---------------------------------------------------------------------------
// Kernel 7: final — recompute chain to a2, dot with active w_out slice,
// block-reduce 9 outputs per m.
__global__ __launch_bounds__(256) void k_final(
    const int* __restrict__ x, const float* __restrict__ conv_w,
    const float* __restrict__ conv_b, const float* __restrict__ w_rank,
    const float* __restrict__ b_rank, const float* __restrict__ w_h1,
    const float* __restrict__ b_h1, const float* __restrict__ w_h2,
    const float* __restrict__ b_h2, const float* __restrict__ w_out,
    const float* __restrict__ ws, float* __restrict__ out, int M) {
  __shared__ float sW[8000];
  __shared__ float sWr[320], sBr[32], sCr[32];
  __shared__ float sW1[1024], sB1[32];
  __shared__ float sW2[512], sB2[16];
  __shared__ float sAl[64], sBe[64], sZ[64], sAl1[64], sBe1[64], sAl2[64], sBe2[64];
  __shared__ float sOC[9];
  __shared__ float sRed[4 * 9];
  for (int i = threadIdx.x; i < 8000; i += 256) sW[i] = conv_w[i];
  for (int i = threadIdx.x; i < 320; i += 256) sWr[i] = w_rank[i];
  for (int i = threadIdx.x; i < 1024; i += 256) sW1[i] = w_h1[i];
  for (int i = threadIdx.x; i < 512; i += 256) sW2[i] = w_h2[i];
  if (threadIdx.x < 32) {
    sBr[threadIdx.x] = b_rank[threadIdx.x];
    sB1[threadIdx.x] = b_h1[threadIdx.x];
    float cu = 0.f;
    for (int s2 = 4; s2 < 10; ++s2) cu += w_rank[threadIdx.x * 10 + s2];
    sCr[threadIdx.x] = cu;
  }
  if (threadIdx.x < 16) sB2[threadIdx.x] = b_h2[threadIdx.x];
  if (threadIdx.x < 9) sOC[threadIdx.x] = ws[WS_OC + threadIdx.x];
  if (threadIdx.x < 64) {
    sAl[threadIdx.x]  = ws[WS_AL0 + threadIdx.x];
    sBe[threadIdx.x]  = ws[WS_BE0 + threadIdx.x];
    sZ[threadIdx.x]   = ws[WS_ZBG + threadIdx.x];
    sAl1[threadIdx.x] = ws[WS_AL1 + threadIdx.x];
    sBe1[threadIdx.x] = ws[WS_BE1 + threadIdx.x];
    sAl2[threadIdx.x] = ws[WS_AL2 + threadIdx.x];
    sBe2[threadIdx.x] = ws[WS_BE2 + threadIdx.x];
  }
  __syncthreads();
  const int tid = threadIdx.x;
  const int y = tid & 3, k = tid >> 2;
  const int wave = tid >> 6, lane = tid & 63;
  const float cb = conv_b[k];
  const float al = sAl[k], be = sBe[k], zbg = sZ[k];
  const float al1 = sAl1[k], be1 = sBe1[k];
  const float al2 = sAl2[k], be2 = sBe2[k];
  const float* Wk = &sW[k * 125];
  for (int m = blockIdx.x; m < M; m += gridDim.x) {
    int r[5], c[5];
#pragma unroll
    for (int cc = 0; cc < 5; ++cc) {
      r[cc] = x[m * 10 + cc * 2];
      c[cc] = x[m * 10 + cc * 2 + 1];
    }
    float a0[4];
#pragma unroll
    for (int xx = 0; xx < 4; ++xx) {
      float v = cb;
#pragma unroll
      for (int cc = 0; cc < 5; ++cc) {
        int di = r[cc] - y, dj = c[cc] - xx;
        if (di >= 0 && di < 5 && dj >= 0 && dj < 5) v += Wk[cc * 25 + di * 5 + dj];
      }
      a0[xx] = fmaxf(al * v + be, 0.f);
    }
    float r1[32];
#pragma unroll
    for (int o = 0; o < 32; ++o) {
      float acc = sBr[o] + zbg * sCr[o];
#pragma unroll
      for (int xx = 0; xx < 4; ++xx) acc += a0[xx] * sWr[o * 10 + xx];
      r1[o] = fmaxf(acc, 0.f);
    }
    float a1[32];
#pragma unroll
    for (int o = 0; o < 32; ++o) {
      float acc = sB1[o];
#pragma unroll
      for (int i = 0; i < 32; ++i) acc += r1[i] * sW1[o * 32 + i];
      a1[o] = fmaxf(al1 * acc + be1, 0.f);
    }
    float a2[16];
#pragma unroll
    for (int p = 0; p < 16; ++p) {
      float acc = sB2[p];
#pragma unroll
      for (int o = 0; o < 32; ++o) acc += a1[o] * sW2[p * 32 + o];
      a2[p] = fmaxf(al2 * acc + be2, 0.f);
    }
    float po[9];
#pragma unroll
    for (int j = 0; j < 9; ++j) {
      const float* wo = &w_out[j * 11264 + k * 176 + y * 16];
      float acc = 0.f;
#pragma unroll
      for (int p = 0; p < 16; ++p) acc += a2[p] * wo[p];
      po[j] = acc;
    }
#pragma unroll
    for (int j = 0; j < 9; ++j) {
      float v = po[j];
      v += __shfl_xor(v, 1);
      v += __shfl_xor(v, 2);
      v += __shfl_xor(v, 4);
      v += __shfl_xor(v, 8);
      v += __shfl_xor(v, 16);
      v += __shfl_xor(v, 32);
      po[j] = v;
    }
    if (lane == 0) {
#pragma unroll
      for (int j = 0; j < 9; ++j) sRed[wave * 9 + j] = po[j];
    }
    __syncthreads();
    if (tid < 9) {
      float acc = sOC[tid];
#pragma unroll
      for (int w2 = 0; w2 < 4; ++w2) acc += sRed[w2 * 9 + tid];
      out[m * 9 + tid] = acc;
    }
    __syncthreads();
  }
}

// ---------------------------------------------------------------------------
extern "C" void kernel_launch(void* const* d_in, const int* in_sizes, int n_in,
                              void* d_out, int out_size, void* d_ws, size_t ws_size,
                              hipStream_t stream) {
  const int*   x      = (const int*)d_in[0];
  const float* conv_w = (const float*)d_in[1];
  const float* conv_b = (const float*)d_in[2];
  const float* bn0_g  = (const float*)d_in[3];
  const float* bn0_b  = (const float*)d_in[4];
  const float* w_rank = (const float*)d_in[5];
  const float* b_rank = (const float*)d_in[6];
  const float* w_h1   = (const float*)d_in[7];
  const float* b_h1   = (const float*)d_in[8];
  const float* bn1_g  = (const float*)d_in[9];
  const float* bn1_b  = (const float*)d_in[10];
  const float* w_h2   = (const float*)d_in[11];
  const float* b_h2   = (const float*)d_in[12];
  const float* bn2_g  = (const float*)d_in[13];
  const float* bn2_b  = (const float*)d_in[14];
  const float* w_out  = (const float*)d_in[15];
  const float* b_out  = (const float*)d_in[16];
  float* out = (float*)d_out;
  float* ws  = (float*)d_ws;
  const int M = in_sizes[0] / 10;

  hipMemsetAsync(ws, 0, 384 * sizeof(float), stream);
  k_stats0<<<256, 256, 0, stream>>>(x, conv_w, conv_b, ws, M);
  k_fin0<<<1, 64, 0, stream>>>(conv_b, bn0_g, bn0_b, w_rank, b_rank, w_h1, b_h1, ws, M);
  k_stats1<<<1024, 256, 0, stream>>>(x, conv_w, conv_b, w_rank, b_rank, w_h1, b_h1, ws, M);
  k_fin1<<<1, 64, 0, stream>>>(bn1_g, bn1_b, w_h2, b_h2, ws, M);
  k_stats2<<<1024, 256, 0, stream>>>(x, conv_w, conv_b, w_rank, b_rank, w_h1, b_h1,
                                     w_h2, b_h2, ws, M);
  k_fin2<<<1, 64, 0, stream>>>(bn2_g, bn2_b, w_out, b_out, ws, M);
  k_final<<<1024, 256, 0, stream>>>(x, conv_w, conv_b, w_rank, b_rank, w_h1, b_h1,
                                    w_h2, b_h2, w_out, ws, out, M);
}

// Round 2
// 559.820 us; speedup vs baseline: 9.0002x; 9.0002x over previous
//
#include <hip/hip_runtime.h>
#include <hip/hip_bf16.h>

#define EPSV 1e-5f

// workspace float offsets
#define WS_SUM0   0
#define WS_SSQ0   64
#define WS_SUM1   128
#define WS_SSQ1   192
#define WS_SUM2   256
#define WS_SSQ2   320
#define WS_AL0    384
#define WS_BE0    448
#define WS_ZBG    512
#define WS_T1BG   576      // 64*32
#define WS_AL1    2624
#define WS_BE1    2688
#define WS_T2BG   2752     // 64*16
#define WS_AL2    3776
#define WS_BE2    3840
#define WS_A2BG   3904     // 64*16
#define WS_OC     4928     // 9 used

// Repacked conv weights in LDS: only di,dj in [0,3] are reachable (r,s <= 3).
// Layout: sW[k*81 + cc*16 + di*4 + dj]  (stride 81 -> odd vs 32 banks)
#define CONV_LDS 5184

__device__ __forceinline__ void stage_conv(float* sW, const float* __restrict__ conv_w,
                                           int nthr) {
  for (int i = threadIdx.x; i < 8000; i += nthr) {
    int k = i / 125, rem = i - k * 125;
    int cc = rem / 25, r2 = rem - cc * 25;
    int di = r2 / 5, dj = r2 - di * 5;
    if (di < 4 && dj < 4) sW[k * 81 + cc * 16 + di * 4 + dj] = conv_w[i];
  }
}

// ---------------------------------------------------------------------------
// Kernel 1: BN0 statistics over the active 16 conv positions (y<4, x<4).
__global__ __launch_bounds__(256) void k_stats0(
    const int* __restrict__ x, const float* __restrict__ conv_w,
    const float* __restrict__ conv_b, float* __restrict__ ws, int M) {
  __shared__ float sW[CONV_LDS];
  stage_conv(sW, conv_w, 256);
  __syncthreads();
  const int tid = threadIdx.x;
  const int mg = tid & 3;
  const int k  = tid >> 2;
  const float cb = conv_b[k];
  const float* Wk = &sW[k * 81];
  float s = 0.f, ss = 0.f;
  for (int m = blockIdx.x * 4 + mg; m < M; m += gridDim.x * 4) {
    int r[5], c[5];
    const int2* xp = (const int2*)(x + m * 10);
#pragma unroll
    for (int cc = 0; cc < 5; ++cc) { int2 t = xp[cc]; r[cc] = t.x; c[cc] = t.y; }
#pragma unroll
    for (int y = 0; y < 4; ++y) {
#pragma unroll
      for (int xx = 0; xx < 4; ++xx) {
        float v = cb;
#pragma unroll
        for (int cc = 0; cc < 5; ++cc) {
          int di = r[cc] - y, dj = c[cc] - xx;
          if ((di | dj) >= 0) v += Wk[cc * 16 + di * 4 + dj];
        }
        s += v;
        ss += v * v;
      }
      __builtin_amdgcn_sched_barrier(0);
    }
  }
  s  += __shfl_xor(s, 1);  s  += __shfl_xor(s, 2);
  ss += __shfl_xor(ss, 1); ss += __shfl_xor(ss, 2);
  if (mg == 0) {
    atomicAdd(&ws[WS_SUM0 + k], s);
    atomicAdd(&ws[WS_SSQ0 + k], ss);
  }
}

// ---------------------------------------------------------------------------
// Kernel 2: finalize BN0; background chain r1_bg -> t1_bg; seed BN1 stats.
__global__ __launch_bounds__(64) void k_fin0(
    const float* __restrict__ conv_b, const float* __restrict__ g0,
    const float* __restrict__ b0, const float* __restrict__ w_rank,
    const float* __restrict__ b_rank, const float* __restrict__ w_h1,
    const float* __restrict__ b_h1, float* __restrict__ ws, int M) {
  __shared__ float sS[32];
  const int t = threadIdx.x;
  if (t < 32) {
    float su = 0.f;
    for (int s2 = 0; s2 < 10; ++s2) su += w_rank[t * 10 + s2];
    sS[t] = su;
  }
  __syncthreads();
  const int k = t;
  const float n0 = 110.f * (float)M;
  const float cb = conv_b[k];
  const float S  = ws[WS_SUM0 + k] + 94.f * (float)M * cb;
  const float SS = ws[WS_SSQ0 + k] + 94.f * (float)M * cb * cb;
  const float mu = S / n0;
  const float var = SS / n0 - mu * mu;
  const float rstd = rsqrtf(var + EPSV);
  const float al = rstd * g0[k];
  const float be = b0[k] - mu * al;
  ws[WS_AL0 + k] = al;
  ws[WS_BE0 + k] = be;
  const float zbg = fmaxf(cb * al + be, 0.f);
  ws[WS_ZBG + k] = zbg;
  float r1bg[32];
#pragma unroll
  for (int o = 0; o < 32; ++o) r1bg[o] = fmaxf(zbg * sS[o] + b_rank[o], 0.f);
  float sb = 0.f, ssb = 0.f;
  for (int o = 0; o < 32; ++o) {
    float acc = b_h1[o];
#pragma unroll
    for (int i = 0; i < 32; ++i) acc += r1bg[i] * w_h1[o * 32 + i];
    ws[WS_T1BG + k * 32 + o] = acc;
    sb += acc;
    ssb += acc * acc;
  }
  ws[WS_SUM1 + k] = 7.f * (float)M * sb;
  ws[WS_SSQ1 + k] = 7.f * (float)M * ssb;
}

// ---------------------------------------------------------------------------
// Kernel 3: BN1 statistics: recompute v -> a0 -> r1 -> t1 over active rows.
__global__ __launch_bounds__(256) void k_stats1(
    const int* __restrict__ x, const float* __restrict__ conv_w,
    const float* __restrict__ conv_b, const float* __restrict__ w_rank,
    const float* __restrict__ b_rank, const float* __restrict__ w_h1,
    const float* __restrict__ b_h1, float* __restrict__ ws, int M) {
  __shared__ float sW[CONV_LDS];
  __shared__ float sWr[320], sBr[32], sCr[32];
  __shared__ float sW1[1024], sB1[32];
  __shared__ float sAl[64], sBe[64], sZ[64];
  stage_conv(sW, conv_w, 256);
  for (int i = threadIdx.x; i < 320; i += 256) sWr[i] = w_rank[i];
  for (int i = threadIdx.x; i < 1024; i += 256) sW1[i] = w_h1[i];
  if (threadIdx.x < 32) {
    sBr[threadIdx.x] = b_rank[threadIdx.x];
    sB1[threadIdx.x] = b_h1[threadIdx.x];
    float cu = 0.f;
    for (int s2 = 4; s2 < 10; ++s2) cu += w_rank[threadIdx.x * 10 + s2];
    sCr[threadIdx.x] = cu;
  }
  if (threadIdx.x < 64) {
    sAl[threadIdx.x] = ws[WS_AL0 + threadIdx.x];
    sBe[threadIdx.x] = ws[WS_BE0 + threadIdx.x];
    sZ[threadIdx.x]  = ws[WS_ZBG + threadIdx.x];
  }
  __syncthreads();
  const int tid = threadIdx.x;
  const int y = tid & 3, k = tid >> 2;
  const float cb = conv_b[k];
  const float al = sAl[k], be = sBe[k], zbg = sZ[k];
  const float* Wk = &sW[k * 81];
  float s1 = 0.f, ss1 = 0.f;
  for (int m = blockIdx.x; m < M; m += gridDim.x) {
    int r[5], c[5];
    const int2* xp = (const int2*)(x + m * 10);
#pragma unroll
    for (int cc = 0; cc < 5; ++cc) { int2 t = xp[cc]; r[cc] = t.x; c[cc] = t.y; }
    float a0[4];
#pragma unroll
    for (int xx = 0; xx < 4; ++xx) {
      float v = cb;
#pragma unroll
      for (int cc = 0; cc < 5; ++cc) {
        int di = r[cc] - y, dj = c[cc] - xx;
        if ((di | dj) >= 0) v += Wk[cc * 16 + di * 4 + dj];
      }
      a0[xx] = fmaxf(al * v + be, 0.f);
    }
    __builtin_amdgcn_sched_barrier(0);
    float r1[32];
#pragma unroll
    for (int o = 0; o < 32; ++o) {
      float acc = sBr[o] + zbg * sCr[o];
#pragma unroll
      for (int xx = 0; xx < 4; ++xx) acc += a0[xx] * sWr[o * 10 + xx];
      r1[o] = fmaxf(acc, 0.f);
    }
    __builtin_amdgcn_sched_barrier(0);
#pragma unroll
    for (int ch = 0; ch < 4; ++ch) {
#pragma unroll
      for (int u = 0; u < 8; ++u) {
        const int o = ch * 8 + u;
        float acc = sB1[o];
#pragma unroll
        for (int i = 0; i < 32; ++i) acc += r1[i] * sW1[o * 32 + i];
        s1 += acc;
        ss1 += acc * acc;
      }
      __builtin_amdgcn_sched_barrier(0);
    }
  }
  s1  += __shfl_xor(s1, 1);  s1  += __shfl_xor(s1, 2);
  ss1 += __shfl_xor(ss1, 1); ss1 += __shfl_xor(ss1, 2);
  if (y == 0) {
    atomicAdd(&ws[WS_SUM1 + k], s1);
    atomicAdd(&ws[WS_SSQ1 + k], ss1);
  }
}

// ---------------------------------------------------------------------------
// Kernel 4: finalize BN1; background a1_bg -> t2_bg; seed BN2 stats.
__global__ __launch_bounds__(64) void k_fin1(
    const float* __restrict__ g1, const float* __restrict__ b1,
    const float* __restrict__ w_h2, const float* __restrict__ b_h2,
    float* __restrict__ ws, int M) {
  const int k = threadIdx.x;
  const float n1 = (float)M * 11.f * 32.f;
  const float S = ws[WS_SUM1 + k], SS = ws[WS_SSQ1 + k];
  const float mu = S / n1;
  const float var = SS / n1 - mu * mu;
  const float rstd = rsqrtf(var + EPSV);
  const float al = rstd * g1[k];
  const float be = b1[k] - mu * al;
  ws[WS_AL1 + k] = al;
  ws[WS_BE1 + k] = be;
  float a1bg[32];
#pragma unroll
  for (int o = 0; o < 32; ++o)
    a1bg[o] = fmaxf(al * ws[WS_T1BG + k * 32 + o] + be, 0.f);
  float sb = 0.f, ssb = 0.f;
  for (int p = 0; p < 16; ++p) {
    float acc = b_h2[p];
#pragma unroll
    for (int o = 0; o < 32; ++o) acc += a1bg[o] * w_h2[p * 32 + o];
    ws[WS_T2BG + k * 16 + p] = acc;
    sb += acc;
    ssb += acc * acc;
  }
  ws[WS_SUM2 + k] = 7.f * (float)M * sb;
  ws[WS_SSQ2 + k] = 7.f * (float)M * ssb;
}

// ---------------------------------------------------------------------------
// Kernel 5: BN2 statistics: chain through t2 on active rows, chunked a1.
__global__ __launch_bounds__(256) void k_stats2(
    const int* __restrict__ x, const float* __restrict__ conv_w,
    const float* __restrict__ conv_b, const float* __restrict__ w_rank,
    const float* __restrict__ b_rank, const float* __restrict__ w_h1,
    const float* __restrict__ b_h1, const float* __restrict__ w_h2,
    const float* __restrict__ b_h2, float* __restrict__ ws, int M) {
  __shared__ float sW[CONV_LDS];
  __shared__ float sWr[320], sBr[32], sCr[32];
  __shared__ float sW1[1024], sB1[32];
  __shared__ float sW2[512], sB2[16];
  __shared__ float sAl[64], sBe[64], sZ[64], sAl1[64], sBe1[64];
  stage_conv(sW, conv_w, 256);
  for (int i = threadIdx.x; i < 320; i += 256) sWr[i] = w_rank[i];
  for (int i = threadIdx.x; i < 1024; i += 256) sW1[i] = w_h1[i];
  for (int i = threadIdx.x; i < 512; i += 256) sW2[i] = w_h2[i];
  if (threadIdx.x < 32) {
    sBr[threadIdx.x] = b_rank[threadIdx.x];
    sB1[threadIdx.x] = b_h1[threadIdx.x];
    float cu = 0.f;
    for (int s2 = 4; s2 < 10; ++s2) cu += w_rank[threadIdx.x * 10 + s2];
    sCr[threadIdx.x] = cu;
  }
  if (threadIdx.x < 16) sB2[threadIdx.x] = b_h2[threadIdx.x];
  if (threadIdx.x < 64) {
    sAl[threadIdx.x]  = ws[WS_AL0 + threadIdx.x];
    sBe[threadIdx.x]  = ws[WS_BE0 + threadIdx.x];
    sZ[threadIdx.x]   = ws[WS_ZBG + threadIdx.x];
    sAl1[threadIdx.x] = ws[WS_AL1 + threadIdx.x];
    sBe1[threadIdx.x] = ws[WS_BE1 + threadIdx.x];
  }
  __syncthreads();
  const int tid = threadIdx.x;
  const int y = tid & 3, k = tid >> 2;
  const float cb = conv_b[k];
  const float al = sAl[k], be = sBe[k], zbg = sZ[k];
  const float al1 = sAl1[k], be1 = sBe1[k];
  const float* Wk = &sW[k * 81];
  float s2a = 0.f, ss2a = 0.f;
  for (int m = blockIdx.x; m < M; m += gridDim.x) {
    int r[5], c[5];
    const int2* xp = (const int2*)(x + m * 10);
#pragma unroll
    for (int cc = 0; cc < 5; ++cc) { int2 t = xp[cc]; r[cc] = t.x; c[cc] = t.y; }
    float a0[4];
#pragma unroll
    for (int xx = 0; xx < 4; ++xx) {
      float v = cb;
#pragma unroll
      for (int cc = 0; cc < 5; ++cc) {
        int di = r[cc] - y, dj = c[cc] - xx;
        if ((di | dj) >= 0) v += Wk[cc * 16 + di * 4 + dj];
      }
      a0[xx] = fmaxf(al * v + be, 0.f);
    }
    __builtin_amdgcn_sched_barrier(0);
    float r1[32];
#pragma unroll
    for (int o = 0; o < 32; ++o) {
      float acc = sBr[o] + zbg * sCr[o];
#pragma unroll
      for (int xx = 0; xx < 4; ++xx) acc += a0[xx] * sWr[o * 10 + xx];
      r1[o] = fmaxf(acc, 0.f);
    }
    __builtin_amdgcn_sched_barrier(0);
    float t2[16];
#pragma unroll
    for (int p = 0; p < 16; ++p) t2[p] = sB2[p];
#pragma unroll
    for (int ch = 0; ch < 4; ++ch) {
      float a1c[8];
#pragma unroll
      for (int u = 0; u < 8; ++u) {
        const int o = ch * 8 + u;
        float acc = sB1[o];
#pragma unroll
        for (int i = 0; i < 32; ++i) acc += r1[i] * sW1[o * 32 + i];
        a1c[u] = fmaxf(al1 * acc + be1, 0.f);
      }
      __builtin_amdgcn_sched_barrier(0);
#pragma unroll
      for (int p = 0; p < 16; ++p) {
        float acc = t2[p];
#pragma unroll
        for (int u = 0; u < 8; ++u) acc += a1c[u] * sW2[p * 32 + ch * 8 + u];
        t2[p] = acc;
      }
      __builtin_amdgcn_sched_barrier(0);
    }
#pragma unroll
    for (int p = 0; p < 16; ++p) { s2a += t2[p]; ss2a += t2[p] * t2[p]; }
  }
  s2a  += __shfl_xor(s2a, 1);  s2a  += __shfl_xor(s2a, 2);
  ss2a += __shfl_xor(ss2a, 1); ss2a += __shfl_xor(ss2a, 2);
  if (y == 0) {
    atomicAdd(&ws[WS_SUM2 + k], s2a);
    atomicAdd(&ws[WS_SSQ2 + k], ss2a);
  }
}

// ---------------------------------------------------------------------------
// Kernel 6: finalize BN2; background a2_bg; background output constant.
__global__ __launch_bounds__(64) void k_fin2(
    const float* __restrict__ g2, const float* __restrict__ b2,
    const float* __restrict__ w_out, const float* __restrict__ b_out,
    float* __restrict__ ws, int M) {
  __shared__ float red[64 * 9];
  const int k = threadIdx.x;
  const float n2 = (float)M * 11.f * 16.f;
  const float S = ws[WS_SUM2 + k], SS = ws[WS_SSQ2 + k];
  const float mu = S / n2;
  const float var = SS / n2 - mu * mu;
  const float rstd = rsqrtf(var + EPSV);
  const float al = rstd * g2[k];
  const float be = b2[k] - mu * al;
  ws[WS_AL2 + k] = al;
  ws[WS_BE2 + k] = be;
  float a2bg[16];
#pragma unroll
  for (int p = 0; p < 16; ++p) {
    a2bg[p] = fmaxf(al * ws[WS_T2BG + k * 16 + p] + be, 0.f);
    ws[WS_A2BG + k * 16 + p] = a2bg[p];
  }
  for (int j = 0; j < 9; ++j) {
    float acc = 0.f;
#pragma unroll
    for (int p = 0; p < 16; ++p) {
      float wsum = 0.f;
#pragma unroll
      for (int yy = 4; yy < 11; ++yy)
        wsum += w_out[j * 11264 + k * 176 + yy * 16 + p];
      acc += a2bg[p] * wsum;
    }
    red[k * 9 + j] = acc;
  }
  __syncthreads();
  if (k < 9) {
    float acc = b_out[k];
    for (int t = 0; t < 64; ++t) acc += red[t * 9 + k];
    ws[WS_OC + k] = acc;
  }
}

// ---------------------------------------------------------------------------
// Kernel 7: final — full chain, float4 w_out dot, block-reduce 9 outputs.
__global__ __launch_bounds__(256) void k_final(
    const int* __restrict__ x, const float* __restrict__ conv_w,
    const float* __restrict__ conv_b, const float* __restrict__ w_rank,
    const float* __restrict__ b_rank, const float* __restrict__ w_h1,
    const float* __restrict__ b_h1, const float* __restrict__ w_h2,
    const float* __restrict__ b_h2, const float* __restrict__ w_out,
    const float* __restrict__ ws, float* __restrict__ out, int M) {
  __shared__ float sW[CONV_LDS];
  __shared__ float sWr[320], sBr[32], sCr[32];
  __shared__ float sW1[1024], sB1[32];
  __shared__ float sW2[512], sB2[16];
  __shared__ float sAl[64], sBe[64], sZ[64], sAl1[64], sBe1[64], sAl2[64], sBe2[64];
  __shared__ float sOC[9];
  __shared__ float sRed[4 * 9];
  stage_conv(sW, conv_w, 256);
  for (int i = threadIdx.x; i < 320; i += 256) sWr[i] = w_rank[i];
  for (int i = threadIdx.x; i < 1024; i += 256) sW1[i] = w_h1[i];
  for (int i = threadIdx.x; i < 512; i += 256) sW2[i] = w_h2[i];
  if (threadIdx.x < 32) {
    sBr[threadIdx.x] = b_rank[threadIdx.x];
    sB1[threadIdx.x] = b_h1[threadIdx.x];
    float cu = 0.f;
    for (int s2 = 4; s2 < 10; ++s2) cu += w_rank[threadIdx.x * 10 + s2];
    sCr[threadIdx.x] = cu;
  }
  if (threadIdx.x < 16) sB2[threadIdx.x] = b_h2[threadIdx.x];
  if (threadIdx.x < 9) sOC[threadIdx.x] = ws[WS_OC + threadIdx.x];
  if (threadIdx.x < 64) {
    sAl[threadIdx.x]  = ws[WS_AL0 + threadIdx.x];
    sBe[threadIdx.x]  = ws[WS_BE0 + threadIdx.x];
    sZ[threadIdx.x]   = ws[WS_ZBG + threadIdx.x];
    sAl1[threadIdx.x] = ws[WS_AL1 + threadIdx.x];
    sBe1[threadIdx.x] = ws[WS_BE1 + threadIdx.x];
    sAl2[threadIdx.x] = ws[WS_AL2 + threadIdx.x];
    sBe2[threadIdx.x] = ws[WS_BE2 + threadIdx.x];
  }
  __syncthreads();
  const int tid = threadIdx.x;
  const int y = tid & 3, k = tid >> 2;
  const int wave = tid >> 6, lane = tid & 63;
  const float cb = conv_b[k];
  const float al = sAl[k], be = sBe[k], zbg = sZ[k];
  const float al1 = sAl1[k], be1 = sBe1[k];
  const float al2 = sAl2[k], be2 = sBe2[k];
  const float* Wk = &sW[k * 81];
  // active w_out slice for this (k,y): 16 consecutive floats per j
  const float4* wo = (const float4*)(w_out + k * 176 + y * 16);
  for (int m = blockIdx.x; m < M; m += gridDim.x) {
    int r[5], c[5];
    const int2* xp = (const int2*)(x + m * 10);
#pragma unroll
    for (int cc = 0; cc < 5; ++cc) { int2 t = xp[cc]; r[cc] = t.x; c[cc] = t.y; }
    float a0[4];
#pragma unroll
    for (int xx = 0; xx < 4; ++xx) {
      float v = cb;
#pragma unroll
      for (int cc = 0; cc < 5; ++cc) {
        int di = r[cc] - y, dj = c[cc] - xx;
        if ((di | dj) >= 0) v += Wk[cc * 16 + di * 4 + dj];
      }
      a0[xx] = fmaxf(al * v + be, 0.f);
    }
    __builtin_amdgcn_sched_barrier(0);
    float r1[32];
#pragma unroll
    for (int o = 0; o < 32; ++o) {
      float acc = sBr[o] + zbg * sCr[o];
#pragma unroll
      for (int xx = 0; xx < 4; ++xx) acc += a0[xx] * sWr[o * 10 + xx];
      r1[o] = fmaxf(acc, 0.f);
    }
    __builtin_amdgcn_sched_barrier(0);
    float t2[16];
#pragma unroll
    for (int p = 0; p < 16; ++p) t2[p] = sB2[p];
#pragma unroll
    for (int ch = 0; ch < 4; ++ch) {
      float a1c[8];
#pragma unroll
      for (int u = 0; u < 8; ++u) {
        const int o = ch * 8 + u;
        float acc = sB1[o];
#pragma unroll
        for (int i = 0; i < 32; ++i) acc += r1[i] * sW1[o * 32 + i];
        a1c[u] = fmaxf(al1 * acc + be1, 0.f);
      }
      __builtin_amdgcn_sched_barrier(0);
#pragma unroll
      for (int p = 0; p < 16; ++p) {
        float acc = t2[p];
#pragma unroll
        for (int u = 0; u < 8; ++u) acc += a1c[u] * sW2[p * 32 + ch * 8 + u];
        t2[p] = acc;
      }
      __builtin_amdgcn_sched_barrier(0);
    }
    float a2[16];
#pragma unroll
    for (int p = 0; p < 16; ++p) a2[p] = fmaxf(al2 * t2[p] + be2, 0.f);
    float po[9];
#pragma unroll
    for (int j = 0; j < 9; ++j) {
      float4 w0 = wo[j * 2816 + 0], w1 = wo[j * 2816 + 1];
      float4 w2 = wo[j * 2816 + 2], w3 = wo[j * 2816 + 3];
      po[j] = a2[0] * w0.x + a2[1] * w0.y + a2[2] * w0.z + a2[3] * w0.w
            + a2[4] * w1.x + a2[5] * w1.y + a2[6] * w1.z + a2[7] * w1.w
            + a2[8] * w2.x + a2[9] * w2.y + a2[10] * w2.z + a2[11] * w2.w
            + a2[12] * w3.x + a2[13] * w3.y + a2[14] * w3.z + a2[15] * w3.w;
    }
#pragma unroll
    for (int j = 0; j < 9; ++j) {
      float v = po[j];
      v += __shfl_xor(v, 1);
      v += __shfl_xor(v, 2);
      v += __shfl_xor(v, 4);
      v += __shfl_xor(v, 8);
      v += __shfl_xor(v, 16);
      v += __shfl_xor(v, 32);
      po[j] = v;
    }
    if (lane == 0) {
#pragma unroll
      for (int j = 0; j < 9; ++j) sRed[wave * 9 + j] = po[j];
    }
    __syncthreads();
    if (tid < 9) {
      float acc = sOC[tid];
#pragma unroll
      for (int w2i = 0; w2i < 4; ++w2i) acc += sRed[w2i * 9 + tid];
      out[m * 9 + tid] = acc;
    }
    __syncthreads();
  }
}

// ---------------------------------------------------------------------------
extern "C" void kernel_launch(void* const* d_in, const int* in_sizes, int n_in,
                              void* d_out, int out_size, void* d_ws, size_t ws_size,
                              hipStream_t stream) {
  const int*   x      = (const int*)d_in[0];
  const float* conv_w = (const float*)d_in[1];
  const float* conv_b = (const float*)d_in[2];
  const float* bn0_g  = (const float*)d_in[3];
  const float* bn0_b  = (const float*)d_in[4];
  const float* w_rank = (const float*)d_in[5];
  const float* b_rank = (const float*)d_in[6];
  const float* w_h1   = (const float*)d_in[7];
  const float* b_h1   = (const float*)d_in[8];
  const float* bn1_g  = (const float*)d_in[9];
  const float* bn1_b  = (const float*)d_in[10];
  const float* w_h2   = (const float*)d_in[11];
  const float* b_h2   = (const float*)d_in[12];
  const float* bn2_g  = (const float*)d_in[13];
  const float* bn2_b  = (const float*)d_in[14];
  const float* w_out  = (const float*)d_in[15];
  const float* b_out  = (const float*)d_in[16];
  float* out = (float*)d_out;
  float* ws  = (float*)d_ws;
  const int M = in_sizes[0] / 10;

  hipMemsetAsync(ws, 0, 384 * sizeof(float), stream);
  k_stats0<<<256, 256, 0, stream>>>(x, conv_w, conv_b, ws, M);
  k_fin0<<<1, 64, 0, stream>>>(conv_b, bn0_g, bn0_b, w_rank, b_rank, w_h1, b_h1, ws, M);
  k_stats1<<<1024, 256, 0, stream>>>(x, conv_w, conv_b, w_rank, b_rank, w_h1, b_h1, ws, M);
  k_fin1<<<1, 64, 0, stream>>>(bn1_g, bn1_b, w_h2, b_h2, ws, M);
  k_stats2<<<1024, 256, 0, stream>>>(x, conv_w, conv_b, w_rank, b_rank, w_h1, b_h1,
                                     w_h2, b_h2, ws, M);
  k_fin2<<<1, 64, 0, stream>>>(bn2_g, bn2_b, w_out, b_out, ws, M);
  k_final<<<1024, 256, 0, stream>>>(x, conv_w, conv_b, w_rank, b_rank, w_h1, b_h1,
                                    w_h2, b_h2, w_out, ws, out, M);
}